// Round 2
// baseline (2699.616 us; speedup 1.0000x reference)
//
#include <hip/hip_runtime.h>
#include <hip/hip_fp16.h>
#include <cstdint>
#include <cstddef>

// ---------------------------------------------------------------------------
// Gated delta-rule block for MI355X (gfx950).
// Workspace budget: 177 MB (guarded — if ws_size is smaller we memset d_out
// and return, turning a crash into an informative absmax failure).
// Layout:
//   [0,64)    xh,xl bf16 split of x          -> reused as obuf (fp32) later
//   [64,80)   wh,wl transposed weight bufs   (reused for each GEMM)
//   [80,144)  pre (fp32 GEMM out; finally holds gpre until k_lngate)
//   [144,176) postk fp16                     -> reused as y bf16 later
//   [176,177) alpha, beta (fp32, 512KB each)
//   d_out     postv fp16 [0,32MB) + postq fp16 [32,64MB) -> final output
// ---------------------------------------------------------------------------

typedef __attribute__((ext_vector_type(8))) short bf16x8;   // 8 bf16 = 4 VGPRs
typedef __attribute__((ext_vector_type(4))) float f32x4;

#define DEV __device__ __forceinline__

DEV unsigned short f2bf(float f) {          // round-to-nearest-even fp32->bf16
  unsigned int u = __float_as_uint(f);
  unsigned int r = (u + 0x7fffu + ((u >> 16) & 1u)) >> 16;
  return (unsigned short)r;
}
DEV float bf2f(unsigned short b) { return __uint_as_float(((unsigned int)b) << 16); }
DEV float sigm(float z) { return 1.f / (1.f + expf(-z)); }

// --------------------------------------------------------------------- split
__global__ __launch_bounds__(256)
void k_split(const float* __restrict__ x, unsigned short* __restrict__ hi,
             unsigned short* __restrict__ lo, int n4) {
  int i = blockIdx.x * 256 + threadIdx.x;
  if (i >= n4) return;
  float4 v = ((const float4*)x)[i];
  float vv[4] = {v.x, v.y, v.z, v.w};
  unsigned short h[4], l[4];
#pragma unroll
  for (int j = 0; j < 4; j++) {
    h[j] = f2bf(vv[j]);
    l[j] = f2bf(vv[j] - bf2f(h[j]));
  }
  *(uint2*)(hi + 4 * (size_t)i) = *(uint2*)h;
  *(uint2*)(lo + 4 * (size_t)i) = *(uint2*)l;
}

// --------------------------------------------------- weight transpose + split
// W [Kd][Nd] fp32 -> ht/lt [Nd][Kd] bf16  (lt may be nullptr)
__global__ __launch_bounds__(256)
void k_transpose_split(const float* __restrict__ W, unsigned short* __restrict__ ht,
                       unsigned short* __restrict__ lt, int Kd, int Nd) {
  __shared__ float tile[32][33];
  int nb = blockIdx.x * 32, kb = blockIdx.y * 32;
  int tx = threadIdx.x & 31, ty = threadIdx.x >> 5;   // 32 x 8
#pragma unroll
  for (int r = 0; r < 32; r += 8)
    tile[ty + r][tx] = W[(size_t)(kb + ty + r) * Nd + nb + tx];
  __syncthreads();
#pragma unroll
  for (int r = 0; r < 32; r += 8) {
    int n = nb + ty + r, kk = kb + tx;
    float v = tile[tx][ty + r];
    unsigned short h = f2bf(v);
    ht[(size_t)n * Kd + kk] = h;
    if (lt) lt[(size_t)n * Kd + kk] = f2bf(v - bf2f(h));
  }
}

// ------------------------------------------------------------- alpha / beta
// one block per x-row; 32 outputs (16 alpha + 16 beta), 8 lanes each
__global__ __launch_bounds__(256)
void k_ab(const float* __restrict__ x, const float* __restrict__ Wa,
          const float* __restrict__ ba, const float* __restrict__ Wb,
          const float* __restrict__ bb, float* __restrict__ alpha,
          float* __restrict__ beta) {
  __shared__ float xs[2048];
  int r = blockIdx.x;
  const float* xr = x + (size_t)r * 2048;
  for (int i = threadIdx.x; i < 2048; i += 256) xs[i] = xr[i];
  __syncthreads();
  int c = threadIdx.x >> 3, e = threadIdx.x & 7;
  int cc = c & 15;
  const float* W = (c < 16) ? Wa : Wb;
  const float* wp = W + cc;
  float s = 0.f;
  for (int k = e * 256; k < e * 256 + 256; k++) s += xs[k] * wp[(size_t)k * 16];
  s += __shfl_xor(s, 1); s += __shfl_xor(s, 2); s += __shfl_xor(s, 4);
  if (e == 0) {
    float bias = (c < 16) ? ba[cc] : bb[cc];
    float v = sigm(s + bias);
    if (c < 16) alpha[(size_t)r * 16 + cc] = v;
    else        beta [(size_t)r * 16 + cc] = v;
  }
}

// --------------------------------------------------------------------- GEMM
// C[M][N] fp32 = A[M][K] @ Bt[N][K]^T, bf16 inputs.
// SPLIT: 3-term precision emulation (Ah*Bh + Ah*Bl + Al*Bh).
// 128x128 tile, BK=32, 4 waves (2x2), each wave 64x64 = 4x4 16x16x32 frags.
// LDS padded stride 40 elems (80B, keeps 16B alignment) to spread banks.
template <bool SPLIT>
__global__ __launch_bounds__(256)
void k_gemm(const unsigned short* __restrict__ Ah, const unsigned short* __restrict__ Al,
            const unsigned short* __restrict__ Bh, const unsigned short* __restrict__ Bl,
            float* __restrict__ C, int M, int N, int Kd) {
  constexpr int LDT = 40;
  extern __shared__ unsigned short smem[];
  unsigned short* sAh = smem;
  unsigned short* sBh = sAh + 128 * LDT;
  unsigned short* sAl = SPLIT ? sBh + 128 * LDT : nullptr;
  unsigned short* sBl = SPLIT ? sAl + 128 * LDT : nullptr;

  int tid = threadIdx.x;
  int row0 = blockIdx.y * 128, col0 = blockIdx.x * 128;
  int srow = tid >> 1;              // staging row 0..127
  int koff = (tid & 1) << 4;        // 0 or 16
  const unsigned short* gAh = Ah + (size_t)(row0 + srow) * Kd + koff;
  const unsigned short* gBh = Bh + (size_t)(col0 + srow) * Kd + koff;
  const unsigned short* gAl = SPLIT ? Al + (size_t)(row0 + srow) * Kd + koff : nullptr;
  const unsigned short* gBl = SPLIT ? Bl + (size_t)(col0 + srow) * Kd + koff : nullptr;
  unsigned short* wA = sAh + srow * LDT + koff;
  unsigned short* wB = sBh + srow * LDT + koff;
  unsigned short* wAl = SPLIT ? sAl + srow * LDT + koff : nullptr;
  unsigned short* wBl = SPLIT ? sBl + srow * LDT + koff : nullptr;

  int l = tid & 63;
  int wv = tid >> 6;
  int wrB = (wv >> 1) * 64, wcB = (wv & 1) * 64;
  int fr = l & 15, kg = l >> 4;
  size_t aoff = (size_t)(wrB + fr) * LDT + kg * 8;
  size_t boff = (size_t)(wcB + fr) * LDT + kg * 8;

  f32x4 acc[4][4];
#pragma unroll
  for (int m = 0; m < 4; m++)
#pragma unroll
    for (int n = 0; n < 4; n++)
#pragma unroll
      for (int r = 0; r < 4; r++) acc[m][n][r] = 0.f;

  for (int k0 = 0; k0 < Kd; k0 += 32) {
    *(bf16x8*)(wA)     = *(const bf16x8*)(gAh + k0);
    *(bf16x8*)(wA + 8) = *(const bf16x8*)(gAh + k0 + 8);
    *(bf16x8*)(wB)     = *(const bf16x8*)(gBh + k0);
    *(bf16x8*)(wB + 8) = *(const bf16x8*)(gBh + k0 + 8);
    if (SPLIT) {
      *(bf16x8*)(wAl)     = *(const bf16x8*)(gAl + k0);
      *(bf16x8*)(wAl + 8) = *(const bf16x8*)(gAl + k0 + 8);
      *(bf16x8*)(wBl)     = *(const bf16x8*)(gBl + k0);
      *(bf16x8*)(wBl + 8) = *(const bf16x8*)(gBl + k0 + 8);
    }
    __syncthreads();

    bf16x8 a_h[4], b_h[4], a_l[4], b_l[4];
#pragma unroll
    for (int i = 0; i < 4; i++) {
      a_h[i] = *(const bf16x8*)(sAh + aoff + (size_t)i * 16 * LDT);
      b_h[i] = *(const bf16x8*)(sBh + boff + (size_t)i * 16 * LDT);
      if (SPLIT) {
        a_l[i] = *(const bf16x8*)(sAl + aoff + (size_t)i * 16 * LDT);
        b_l[i] = *(const bf16x8*)(sBl + boff + (size_t)i * 16 * LDT);
      }
    }
#pragma unroll
    for (int m = 0; m < 4; m++)
#pragma unroll
      for (int n = 0; n < 4; n++) {
        acc[m][n] = __builtin_amdgcn_mfma_f32_16x16x32_bf16(a_h[m], b_h[n], acc[m][n], 0, 0, 0);
        if (SPLIT) {
          acc[m][n] = __builtin_amdgcn_mfma_f32_16x16x32_bf16(a_h[m], b_l[n], acc[m][n], 0, 0, 0);
          acc[m][n] = __builtin_amdgcn_mfma_f32_16x16x32_bf16(a_l[m], b_h[n], acc[m][n], 0, 0, 0);
        }
      }
    __syncthreads();
  }
  // C/D layout (m89-verified): col = lane&15, row = (lane>>4)*4 + reg
#pragma unroll
  for (int m = 0; m < 4; m++) {
    int rb = row0 + wrB + m * 16 + kg * 4;
#pragma unroll
    for (int n = 0; n < 4; n++) {
      int cb = col0 + wcB + n * 16 + fr;
#pragma unroll
      for (int r = 0; r < 4; r++)
        C[(size_t)(rb + r) * N + cb] = acc[m][n][r];
    }
  }
}

// ---------------------------------------------------- causal conv K=4 + silu
// writes fp16 (precision 2^-11 rel — recurrence propagator has norm <= alpha,
// so no amplification downstream)
__global__ __launch_bounds__(256)
void k_conv(const float* __restrict__ pre, const float* __restrict__ w,
            const float* __restrict__ bias, __half* __restrict__ post, float scale) {
  int idx = blockIdx.x * 256 + threadIdx.x;   // over B*T*C = 16,777,216
  int c = idx & 2047;
  int t = (idx >> 11) & 2047;
  float acc = bias[c];
  const float4 wv = *(const float4*)(w + 4 * (size_t)c);
  const float* p = pre + idx;
  if (t >= 3) acc += wv.x * p[-3 * 2048];
  if (t >= 2) acc += wv.y * p[-2 * 2048];
  if (t >= 1) acc += wv.z * p[-2048];
  acc += wv.w * p[0];
  post[idx] = __float2half(scale * (acc / (1.f + expf(-acc))));   // silu * scale
}

// ---------------------------------------------------------------- recurrence
// grid = B*H*4 = 256 blocks; block handles 32 DV-rows of one (b,h).
// thread: row r = tid>>3 (32 rows), k-slice e = tid&7 (16 elems), S in regs.
__global__ __launch_bounds__(256)
void k_recur(const __half* __restrict__ q, const __half* __restrict__ k,
             const __half* __restrict__ v, const float* __restrict__ alpha,
             const float* __restrict__ beta, float* __restrict__ o) {
  constexpr int TB = 32;
  __shared__ float ks[TB][128], qs[TB][128], vs[TB][32], os[TB][32];
  __shared__ float as_[TB], bs_[TB];
  int blk = blockIdx.x;
  int quad = blk & 3, bh = blk >> 2;
  int b = bh >> 4, h = bh & 15;
  int tid = threadIdx.x;
  int r = tid >> 3, e = tid & 7;
  const size_t base = ((size_t)b * 2048) * 2048 + (size_t)h * 128;
  const __half* qb = q + base;
  const __half* kb = k + base;
  const __half* vb = v + base + quad * 32;
  const float* ap = alpha + ((size_t)b * 2048) * 16 + h;
  const float* bp = beta  + ((size_t)b * 2048) * 16 + h;
  float* ob = o + base + quad * 32;

  float S[16];
#pragma unroll
  for (int i = 0; i < 16; i++) S[i] = 0.f;

  for (int t0 = 0; t0 < 2048; t0 += TB) {
    // stage k,q (TB x 128) as 4-half packets
    for (int i = tid; i < TB * 32; i += 256) {
      int tt = i >> 5, d4 = (i & 31) * 4;
      size_t g = (size_t)(t0 + tt) * 2048 + d4;
      union { unsigned long long u; __half h[4]; } pk, pq;
      pk.u = *(const unsigned long long*)(kb + g);
      pq.u = *(const unsigned long long*)(qb + g);
      float4 fk = {__half2float(pk.h[0]), __half2float(pk.h[1]),
                   __half2float(pk.h[2]), __half2float(pk.h[3])};
      float4 fq = {__half2float(pq.h[0]), __half2float(pq.h[1]),
                   __half2float(pq.h[2]), __half2float(pq.h[3])};
      *(float4*)&ks[tt][d4] = fk;
      *(float4*)&qs[tt][d4] = fq;
    }
    // stage v (TB x 32)
    for (int i = tid; i < TB * 8; i += 256) {
      int tt = i >> 3, d4 = (i & 7) * 4;
      union { unsigned long long u; __half h[4]; } pv;
      pv.u = *(const unsigned long long*)(vb + (size_t)(t0 + tt) * 2048 + d4);
      float4 fv = {__half2float(pv.h[0]), __half2float(pv.h[1]),
                   __half2float(pv.h[2]), __half2float(pv.h[3])};
      *(float4*)&vs[tt][d4] = fv;
    }
    if (tid < TB) {
      as_[tid] = ap[(size_t)(t0 + tid) * 16];
      bs_[tid] = bp[(size_t)(t0 + tid) * 16];
    }
    __syncthreads();

    for (int tt = 0; tt < TB; tt++) {
      const float4* kp = (const float4*)&ks[tt][e * 16];
      const float4* qp = (const float4*)&qs[tt][e * 16];
      float kk[16], qq[16];
      *(float4*)(kk + 0) = kp[0]; *(float4*)(kk + 4) = kp[1];
      *(float4*)(kk + 8) = kp[2]; *(float4*)(kk + 12) = kp[3];
      *(float4*)(qq + 0) = qp[0]; *(float4*)(qq + 4) = qp[1];
      *(float4*)(qq + 8) = qp[2]; *(float4*)(qq + 12) = qp[3];
      float p = 0.f;
#pragma unroll
      for (int i = 0; i < 16; i++) p += S[i] * kk[i];
      p += __shfl_xor(p, 1); p += __shfl_xor(p, 2); p += __shfl_xor(p, 4);
      float a = as_[tt];
      float cmul = bs_[tt] * (p - vs[tt][r]);   // beta * err
      float og = 0.f;
#pragma unroll
      for (int i = 0; i < 16; i++) {
        S[i] = a * S[i] - cmul * kk[i];
        og += S[i] * qq[i];
      }
      og += __shfl_xor(og, 1); og += __shfl_xor(og, 2); og += __shfl_xor(og, 4);
      if (e == 0) os[tt][r] = og;
    }
    __syncthreads();
    for (int i = tid; i < TB * 32; i += 256) {
      int tt = i >> 5, d = i & 31;
      ob[(size_t)(t0 + tt) * 2048 + d] = os[tt][d];
    }
    __syncthreads();
  }
}

// ----------------------------------------------------- LayerNorm * gate -> y
// one wave per (b,t,h) row of 128; y written as single bf16
__global__ __launch_bounds__(256)
void k_lngate(const float* __restrict__ o, const float* __restrict__ gpre,
              const float* __restrict__ ln_g, const float* __restrict__ ln_b,
              unsigned short* __restrict__ y) {
  int row = blockIdx.x * 4 + (threadIdx.x >> 6);   // 0 .. B*T*H-1
  int l = threadIdx.x & 63;
  const float* op = o + (size_t)row * 128;
  float2 xv = *(const float2*)(op + l * 2);
  float s = xv.x + xv.y;
#pragma unroll
  for (int off = 1; off < 64; off <<= 1) s += __shfl_xor(s, off);
  float mu = s * (1.f / 128.f);
  float d0 = xv.x - mu, d1 = xv.y - mu;
  float vv = d0 * d0 + d1 * d1;
#pragma unroll
  for (int off = 1; off < 64; off <<= 1) vv += __shfl_xor(vv, off);
  float rstd = 1.f / sqrtf(vv * (1.f / 128.f) + 1e-5f);
  size_t gbase = (size_t)row * 128;
  int d = l * 2;
  float y0 = (d0 * rstd * ln_g[d]     + ln_b[d])     * sigm(gpre[gbase + d]);
  float y1 = (d1 * rstd * ln_g[d + 1] + ln_b[d + 1]) * sigm(gpre[gbase + d + 1]);
  unsigned int h0 = f2bf(y0), h1 = f2bf(y1);
  *(unsigned int*)(y + gbase + d) = h0 | (h1 << 16);
}

// ---------------------------------------------------------------------------
extern "C" void kernel_launch(void* const* d_in, const int* in_sizes, int n_in,
                              void* d_out, int out_size, void* d_ws, size_t ws_size,
                              hipStream_t stream) {
  const float* x   = (const float*)d_in[0];
  const float* Wq  = (const float*)d_in[1];
  const float* Wk  = (const float*)d_in[2];
  const float* Wv  = (const float*)d_in[3];
  const float* Wa  = (const float*)d_in[4];
  const float* ba  = (const float*)d_in[5];
  const float* Wb  = (const float*)d_in[6];
  const float* bb  = (const float*)d_in[7];
  const float* Wg  = (const float*)d_in[8];
  const float* Wo  = (const float*)d_in[9];
  const float* cqw = (const float*)d_in[10];
  const float* cqb = (const float*)d_in[11];
  const float* ckw = (const float*)d_in[12];
  const float* ckb = (const float*)d_in[13];
  const float* cvw = (const float*)d_in[14];
  const float* cvb = (const float*)d_in[15];
  const float* lng = (const float*)d_in[16];
  const float* lnb = (const float*)d_in[17];

  char* ws = (char*)d_ws;
  const size_t MB = 1024 * 1024;
  const size_t NEED = 178 * MB;
  if (ws_size < NEED) {   // deterministic guard: same behavior on every call
    (void)hipMemsetAsync(d_out, 0, (size_t)out_size * 4, stream);
    return;
  }

  unsigned short* xh  = (unsigned short*)(ws);             // 32MB
  unsigned short* xl  = (unsigned short*)(ws + 32 * MB);   // 32MB
  unsigned short* wh  = (unsigned short*)(ws + 64 * MB);   // 8MB
  unsigned short* wl  = (unsigned short*)(ws + 72 * MB);   // 8MB
  float* pre          = (float*)(ws + 80 * MB);            // 64MB (ends as gpre)
  __half* postk       = (__half*)(ws + 144 * MB);          // 32MB
  float* alphab       = (float*)(ws + 176 * MB);           // 512KB
  float* betab        = (float*)(ws + 176 * MB + 512 * 1024); // 512KB
  float* obuf         = (float*)ws;                        // overlaps xh/xl (dead)
  unsigned short* ybf = (unsigned short*)(ws + 144 * MB);  // overlaps postk (dead)
  __half* postv       = (__half*)d_out;                    // 32MB
  __half* postq       = (__half*)d_out + 16777216;         // 32MB

  dim3 gGemm(16, 64);   // (N/128, M/128)
  dim3 gT(64, 64);
  const int smemSplit = 4 * 128 * 40 * 2;
  const int smemPlain = 2 * 128 * 40 * 2;
  const float kscale = 0.08838834764831845f;  // 128^-0.5

  k_split<<<16384, 256, 0, stream>>>(x, xh, xl, 4194304);
  k_ab<<<8192, 256, 0, stream>>>(x, Wa, ba, Wb, bb, alphab, betab);

  k_transpose_split<<<gT, 256, 0, stream>>>(Wq, wh, wl, 2048, 2048);
  k_gemm<true><<<gGemm, 256, smemSplit, stream>>>(xh, xl, wh, wl, pre, 8192, 2048, 2048);
  k_conv<<<65536, 256, 0, stream>>>(pre, cqw, cqb, postq, 1.f);

  k_transpose_split<<<gT, 256, 0, stream>>>(Wk, wh, wl, 2048, 2048);
  k_gemm<true><<<gGemm, 256, smemSplit, stream>>>(xh, xl, wh, wl, pre, 8192, 2048, 2048);
  k_conv<<<65536, 256, 0, stream>>>(pre, ckw, ckb, postk, kscale);

  k_transpose_split<<<gT, 256, 0, stream>>>(Wv, wh, wl, 2048, 2048);
  k_gemm<true><<<gGemm, 256, smemSplit, stream>>>(xh, xl, wh, wl, pre, 8192, 2048, 2048);
  k_conv<<<65536, 256, 0, stream>>>(pre, cvw, cvb, postv, 1.f);

  k_transpose_split<<<gT, 256, 0, stream>>>(Wg, wh, nullptr, 2048, 2048);
  k_gemm<false><<<gGemm, 256, smemPlain, stream>>>(xh, nullptr, wh, nullptr, pre, 8192, 2048, 2048);

  k_recur<<<256, 256, 0, stream>>>(postq, postk, postv, alphab, betab, obuf);
  k_lngate<<<32768, 256, 0, stream>>>(obuf, pre, lng, lnb, ybf);

  k_transpose_split<<<gT, 256, 0, stream>>>(Wo, wh, nullptr, 2048, 2048);
  k_gemm<false><<<gGemm, 256, smemPlain, stream>>>(ybf, nullptr, wh, nullptr, (float*)d_out, 8192, 2048, 2048);
}

// Round 3
// 2279.031 us; speedup vs baseline: 1.1845x; 1.1845x over previous
//
#include <hip/hip_runtime.h>
#include <hip/hip_fp16.h>
#include <cstdint>
#include <cstddef>

// ---------------------------------------------------------------------------
// Gated delta-rule block for MI355X (gfx950).  R3:
//  - k_recur v2: 512 thr, 16-lane k-groups, DPP butterfly reduce (no LDS
//    swizzles), bank-swizzled fp32 LDS cols  (was LDS-pipe-bound at 958us)
//  - k_gemm v2: m97 structure — linear [128][32] LDS tiles staged via
//    __builtin_amdgcn_global_load_lds width=16, 2-barrier loop
// Workspace: 178 MB, guarded.
// ---------------------------------------------------------------------------

typedef __attribute__((ext_vector_type(8))) short bf16x8;   // 8 bf16 = 4 VGPRs
typedef __attribute__((ext_vector_type(4))) float f32x4;

#define DEV __device__ __forceinline__

DEV unsigned short f2bf(float f) {          // round-to-nearest-even fp32->bf16
  unsigned int u = __float_as_uint(f);
  unsigned int r = (u + 0x7fffu + ((u >> 16) & 1u)) >> 16;
  return (unsigned short)r;
}
DEV float bf2f(unsigned short b) { return __uint_as_float(((unsigned int)b) << 16); }
DEV float sigm(float z) { return 1.f / (1.f + expf(-z)); }

// DPP-based cross-lane add: x += lane[ctrl-mapped](x), VALU pipe only.
DEV float dpp_add(float x, int t_bits) { return x + __int_as_float(t_bits); }
#define DPP_STEP(x, ctrl) \
  (x) = (x) + __int_as_float(__builtin_amdgcn_update_dpp( \
            0, __float_as_int(x), (ctrl), 0xF, 0xF, true))

// --------------------------------------------------------------------- split
__global__ __launch_bounds__(256)
void k_split(const float* __restrict__ x, unsigned short* __restrict__ hi,
             unsigned short* __restrict__ lo, int n4) {
  int i = blockIdx.x * 256 + threadIdx.x;
  if (i >= n4) return;
  float4 v = ((const float4*)x)[i];
  float vv[4] = {v.x, v.y, v.z, v.w};
  unsigned short h[4], l[4];
#pragma unroll
  for (int j = 0; j < 4; j++) {
    h[j] = f2bf(vv[j]);
    l[j] = f2bf(vv[j] - bf2f(h[j]));
  }
  *(uint2*)(hi + 4 * (size_t)i) = *(uint2*)h;
  *(uint2*)(lo + 4 * (size_t)i) = *(uint2*)l;
}

// --------------------------------------------------- weight transpose + split
__global__ __launch_bounds__(256)
void k_transpose_split(const float* __restrict__ W, unsigned short* __restrict__ ht,
                       unsigned short* __restrict__ lt, int Kd, int Nd) {
  __shared__ float tile[32][33];
  int nb = blockIdx.x * 32, kb = blockIdx.y * 32;
  int tx = threadIdx.x & 31, ty = threadIdx.x >> 5;   // 32 x 8
#pragma unroll
  for (int r = 0; r < 32; r += 8)
    tile[ty + r][tx] = W[(size_t)(kb + ty + r) * Nd + nb + tx];
  __syncthreads();
#pragma unroll
  for (int r = 0; r < 32; r += 8) {
    int n = nb + ty + r, kk = kb + tx;
    float v = tile[tx][ty + r];
    unsigned short h = f2bf(v);
    ht[(size_t)n * Kd + kk] = h;
    if (lt) lt[(size_t)n * Kd + kk] = f2bf(v - bf2f(h));
  }
}

// ------------------------------------------------------------- alpha / beta
__global__ __launch_bounds__(256)
void k_ab(const float* __restrict__ x, const float* __restrict__ Wa,
          const float* __restrict__ ba, const float* __restrict__ Wb,
          const float* __restrict__ bb, float* __restrict__ alpha,
          float* __restrict__ beta) {
  __shared__ float xs[2048];
  int r = blockIdx.x;
  const float* xr = x + (size_t)r * 2048;
  for (int i = threadIdx.x; i < 2048; i += 256) xs[i] = xr[i];
  __syncthreads();
  int c = threadIdx.x >> 3, e = threadIdx.x & 7;
  int cc = c & 15;
  const float* W = (c < 16) ? Wa : Wb;
  const float* wp = W + cc;
  float s = 0.f;
  for (int k = e * 256; k < e * 256 + 256; k++) s += xs[k] * wp[(size_t)k * 16];
  s += __shfl_xor(s, 1); s += __shfl_xor(s, 2); s += __shfl_xor(s, 4);
  if (e == 0) {
    float bias = (c < 16) ? ba[cc] : bb[cc];
    float v = sigm(s + bias);
    if (c < 16) alpha[(size_t)r * 16 + cc] = v;
    else        beta [(size_t)r * 16 + cc] = v;
  }
}

// --------------------------------------------------------------------- GEMM
// C[M][N] fp32 = A[M][K] @ Bt[N][K]^T, bf16 inputs.  m97 structure:
// linear [128][32] LDS tiles, global_load_lds width=16 staging, BK=32,
// 4 waves (2x2), each wave 64x64 = 4x4 16x16x32 frags.
#define GLDS16(gsrc, ldst)                                                     \
  __builtin_amdgcn_global_load_lds(                                            \
      (const __attribute__((address_space(1))) unsigned int*)(gsrc),           \
      (__attribute__((address_space(3))) unsigned int*)(ldst), 16, 0, 0)

template <bool SPLIT>
__global__ __launch_bounds__(256)
void k_gemm(const unsigned short* __restrict__ Ah, const unsigned short* __restrict__ Al,
            const unsigned short* __restrict__ Bh, const unsigned short* __restrict__ Bl,
            float* __restrict__ C, int M, int N, int Kd) {
  extern __shared__ unsigned short smem[];
  unsigned short* sAh = smem;                          // [128][32] = 8KB
  unsigned short* sBh = sAh + 4096;
  unsigned short* sAl = SPLIT ? sBh + 4096 : nullptr;
  unsigned short* sBl = SPLIT ? sAl + 4096 : nullptr;

  int tid = threadIdx.x;
  int row0 = blockIdx.y * 128, col0 = blockIdx.x * 128;
  int w = tid >> 6, lane = tid & 63;

  // staging map: wave w instr j covers LDS bytes [(2w+j)*1024 + lane*16)
  //   -> tile row (2w+j)*16 + (lane>>2), k-col (lane&3)*8
  int sr0 = w * 32 + (lane >> 2);          // j=0 row
  int sc  = (lane & 3) * 8;
  size_t d0 = (size_t)w * 1024 + (size_t)lane * 8;   // LDS elem offset, j=0
  size_t d1 = d0 + 512;                              // j=1 (+16 rows)
  const unsigned short* gA0 = Ah + (size_t)(row0 + sr0) * Kd + sc;
  const unsigned short* gA1 = gA0 + (size_t)16 * Kd;
  const unsigned short* gB0 = Bh + (size_t)(col0 + sr0) * Kd + sc;
  const unsigned short* gB1 = gB0 + (size_t)16 * Kd;
  const unsigned short *gAl0 = nullptr, *gAl1 = nullptr, *gBl0 = nullptr, *gBl1 = nullptr;
  if (SPLIT) {
    gAl0 = Al + (size_t)(row0 + sr0) * Kd + sc;  gAl1 = gAl0 + (size_t)16 * Kd;
    gBl0 = Bl + (size_t)(col0 + sr0) * Kd + sc;  gBl1 = gBl0 + (size_t)16 * Kd;
  }

  int wrB = (w >> 1) * 64, wcB = (w & 1) * 64;
  int fr = lane & 15, kg = lane >> 4;
  size_t aoff = (size_t)(wrB + fr) * 32 + kg * 8;
  size_t boff = (size_t)(wcB + fr) * 32 + kg * 8;

  f32x4 acc[4][4];
#pragma unroll
  for (int m = 0; m < 4; m++)
#pragma unroll
    for (int n = 0; n < 4; n++)
#pragma unroll
      for (int r = 0; r < 4; r++) acc[m][n][r] = 0.f;

  for (int k0 = 0; k0 < Kd; k0 += 32) {
    GLDS16(gA0 + k0, sAh + d0);
    GLDS16(gA1 + k0, sAh + d1);
    GLDS16(gB0 + k0, sBh + d0);
    GLDS16(gB1 + k0, sBh + d1);
    if (SPLIT) {
      GLDS16(gAl0 + k0, sAl + d0);
      GLDS16(gAl1 + k0, sAl + d1);
      GLDS16(gBl0 + k0, sBl + d0);
      GLDS16(gBl1 + k0, sBl + d1);
    }
    __syncthreads();   // compiler emits vmcnt(0) drain before s_barrier

    bf16x8 a_h[4], b_h[4], a_l[4], b_l[4];
#pragma unroll
    for (int i = 0; i < 4; i++) {
      a_h[i] = *(const bf16x8*)(sAh + aoff + (size_t)i * 16 * 32);
      b_h[i] = *(const bf16x8*)(sBh + boff + (size_t)i * 16 * 32);
      if (SPLIT) {
        a_l[i] = *(const bf16x8*)(sAl + aoff + (size_t)i * 16 * 32);
        b_l[i] = *(const bf16x8*)(sBl + boff + (size_t)i * 16 * 32);
      }
    }
#pragma unroll
    for (int m = 0; m < 4; m++)
#pragma unroll
      for (int n = 0; n < 4; n++) {
        acc[m][n] = __builtin_amdgcn_mfma_f32_16x16x32_bf16(a_h[m], b_h[n], acc[m][n], 0, 0, 0);
        if (SPLIT) {
          acc[m][n] = __builtin_amdgcn_mfma_f32_16x16x32_bf16(a_h[m], b_l[n], acc[m][n], 0, 0, 0);
          acc[m][n] = __builtin_amdgcn_mfma_f32_16x16x32_bf16(a_l[m], b_h[n], acc[m][n], 0, 0, 0);
        }
      }
    __syncthreads();
  }
  // C/D layout (m89-verified): col = lane&15, row = (lane>>4)*4 + reg
#pragma unroll
  for (int m = 0; m < 4; m++) {
    int rb = row0 + wrB + m * 16 + kg * 4;
#pragma unroll
    for (int n = 0; n < 4; n++) {
      int cb = col0 + wcB + n * 16 + fr;
#pragma unroll
      for (int r = 0; r < 4; r++)
        C[(size_t)(rb + r) * N + cb] = acc[m][n][r];
    }
  }
}

// ---------------------------------------------------- causal conv K=4 + silu
__global__ __launch_bounds__(256)
void k_conv(const float* __restrict__ pre, const float* __restrict__ w,
            const float* __restrict__ bias, __half* __restrict__ post, float scale) {
  int idx = blockIdx.x * 256 + threadIdx.x;   // over B*T*C = 16,777,216
  int c = idx & 2047;
  int t = (idx >> 11) & 2047;
  float acc = bias[c];
  const float4 wv = *(const float4*)(w + 4 * (size_t)c);
  const float* p = pre + idx;
  if (t >= 3) acc += wv.x * p[-3 * 2048];
  if (t >= 2) acc += wv.y * p[-2 * 2048];
  if (t >= 1) acc += wv.z * p[-2048];
  acc += wv.w * p[0];
  post[idx] = __float2half(scale * (acc / (1.f + expf(-acc))));   // silu * scale
}

// ---------------------------------------------------------------- recurrence
// grid = B*H*4 = 256 blocks x 512 threads (8 waves, 2/SIMD).
// thread: row r = tid>>4 (32 rows), k-group e = tid&15 (8 elems each).
// S in regs (8 f32).  Reduce over 16 lanes = pure DPP (ror8,ror4,qp2,qp1).
// LDS k/q cols swizzled: col(g) = 8g + 4(g>>2)  -> 2-way banks (free).
__global__ __launch_bounds__(512)
void k_recur(const __half* __restrict__ q, const __half* __restrict__ k,
             const __half* __restrict__ v, const float* __restrict__ alpha,
             const float* __restrict__ beta, float* __restrict__ o) {
  constexpr int TB = 32;
  __shared__ float ks[TB][144], qs[TB][144];
  __shared__ float vs[TB][32], os[TB][32];
  __shared__ float as_[TB], bs_[TB];
  int blk = blockIdx.x;
  int quad = blk & 3, bh = blk >> 2;
  int b = bh >> 4, h = bh & 15;
  int tid = threadIdx.x;
  int r = tid >> 4, e = tid & 15;
  int cf = e * 8 + (e >> 2) * 4;
  const size_t base = ((size_t)b * 2048) * 2048 + (size_t)h * 128;
  const __half* qb = q + base;
  const __half* kb = k + base;
  const __half* vb = v + base + quad * 32;
  const float* ap = alpha + ((size_t)b * 2048) * 16 + h;
  const float* bp = beta  + ((size_t)b * 2048) * 16 + h;
  float* ob = o + base + quad * 32;

  float S[8];
#pragma unroll
  for (int i = 0; i < 8; i++) S[i] = 0.f;

  for (int t0 = 0; t0 < 2048; t0 += TB) {
    {   // stage k,q: thread -> (tt = tid>>4, g = tid&15), 8 halves each
      int tt = tid >> 4, g = tid & 15, col = g * 8 + (g >> 2) * 4;
      union { uint4 u; __half hh[8]; } pk, pq;
      pk.u = *(const uint4*)(kb + (size_t)(t0 + tt) * 2048 + g * 8);
      pq.u = *(const uint4*)(qb + (size_t)(t0 + tt) * 2048 + g * 8);
      float fk[8], fq[8];
#pragma unroll
      for (int j = 0; j < 8; j++) { fk[j] = __half2float(pk.hh[j]); fq[j] = __half2float(pq.hh[j]); }
      *(float4*)&ks[tt][col]     = *(float4*)(fk);
      *(float4*)&ks[tt][col + 4] = *(float4*)(fk + 4);
      *(float4*)&qs[tt][col]     = *(float4*)(fq);
      *(float4*)&qs[tt][col + 4] = *(float4*)(fq + 4);
    }
    if (tid < 256) {   // stage v: (tt = tid>>3, d4 = (tid&7)*4)
      int tt = tid >> 3, d4 = (tid & 7) * 4;
      union { unsigned long long u; __half hh[4]; } pv;
      pv.u = *(const unsigned long long*)(vb + (size_t)(t0 + tt) * 2048 + d4);
      float4 fv = {__half2float(pv.hh[0]), __half2float(pv.hh[1]),
                   __half2float(pv.hh[2]), __half2float(pv.hh[3])};
      *(float4*)&vs[tt][d4] = fv;
    }
    if (tid < TB) {
      as_[tid] = ap[(size_t)(t0 + tid) * 16];
      bs_[tid] = bp[(size_t)(t0 + tid) * 16];
    }
    __syncthreads();

    for (int tt = 0; tt < TB; tt++) {
      float kk[8], qq[8];
      *(float4*)(kk)     = *(const float4*)&ks[tt][cf];
      *(float4*)(kk + 4) = *(const float4*)&ks[tt][cf + 4];
      *(float4*)(qq)     = *(const float4*)&qs[tt][cf];
      *(float4*)(qq + 4) = *(const float4*)&qs[tt][cf + 4];
      float p = 0.f;
#pragma unroll
      for (int i = 0; i < 8; i++) p += S[i] * kk[i];
      // 16-lane butterfly: ror8 (=xor8), then ror4 (valid on 8-periodic
      // values), then quad_perm xor2, xor1 — all VALU-pipe DPP.
      DPP_STEP(p, 0x128);
      DPP_STEP(p, 0x124);
      DPP_STEP(p, 0x4E);
      DPP_STEP(p, 0xB1);
      float a = as_[tt];
      float cm = bs_[tt] * (p - vs[tt][r]);
      float og = 0.f;
#pragma unroll
      for (int i = 0; i < 8; i++) {
        S[i] = a * S[i] - cm * kk[i];
        og += S[i] * qq[i];
      }
      DPP_STEP(og, 0x128);
      DPP_STEP(og, 0x124);
      DPP_STEP(og, 0x4E);
      DPP_STEP(og, 0xB1);
      if (e == 0) os[tt][r] = og;
    }
    __syncthreads();
    for (int i = tid; i < TB * 32; i += 512) {
      int tt = i >> 5, d = i & 31;
      ob[(size_t)(t0 + tt) * 2048 + d] = os[tt][d];
    }
    __syncthreads();
  }
}

// ----------------------------------------------------- LayerNorm * gate -> y
__global__ __launch_bounds__(256)
void k_lngate(const float* __restrict__ o, const float* __restrict__ gpre,
              const float* __restrict__ ln_g, const float* __restrict__ ln_b,
              unsigned short* __restrict__ y) {
  int row = blockIdx.x * 4 + (threadIdx.x >> 6);   // 0 .. B*T*H-1
  int l = threadIdx.x & 63;
  const float* op = o + (size_t)row * 128;
  float2 xv = *(const float2*)(op + l * 2);
  float s = xv.x + xv.y;
#pragma unroll
  for (int off = 1; off < 64; off <<= 1) s += __shfl_xor(s, off);
  float mu = s * (1.f / 128.f);
  float d0 = xv.x - mu, d1 = xv.y - mu;
  float vv = d0 * d0 + d1 * d1;
#pragma unroll
  for (int off = 1; off < 64; off <<= 1) vv += __shfl_xor(vv, off);
  float rstd = 1.f / sqrtf(vv * (1.f / 128.f) + 1e-5f);
  size_t gbase = (size_t)row * 128;
  int d = l * 2;
  float y0 = (d0 * rstd * ln_g[d]     + ln_b[d])     * sigm(gpre[gbase + d]);
  float y1 = (d1 * rstd * ln_g[d + 1] + ln_b[d + 1]) * sigm(gpre[gbase + d + 1]);
  unsigned int h0 = f2bf(y0), h1 = f2bf(y1);
  *(unsigned int*)(y + gbase + d) = h0 | (h1 << 16);
}

// ---------------------------------------------------------------------------
extern "C" void kernel_launch(void* const* d_in, const int* in_sizes, int n_in,
                              void* d_out, int out_size, void* d_ws, size_t ws_size,
                              hipStream_t stream) {
  const float* x   = (const float*)d_in[0];
  const float* Wq  = (const float*)d_in[1];
  const float* Wk  = (const float*)d_in[2];
  const float* Wv  = (const float*)d_in[3];
  const float* Wa  = (const float*)d_in[4];
  const float* ba  = (const float*)d_in[5];
  const float* Wb  = (const float*)d_in[6];
  const float* bb  = (const float*)d_in[7];
  const float* Wg  = (const float*)d_in[8];
  const float* Wo  = (const float*)d_in[9];
  const float* cqw = (const float*)d_in[10];
  const float* cqb = (const float*)d_in[11];
  const float* ckw = (const float*)d_in[12];
  const float* ckb = (const float*)d_in[13];
  const float* cvw = (const float*)d_in[14];
  const float* cvb = (const float*)d_in[15];
  const float* lng = (const float*)d_in[16];
  const float* lnb = (const float*)d_in[17];

  char* ws = (char*)d_ws;
  const size_t MB = 1024 * 1024;
  const size_t NEED = 178 * MB;
  if (ws_size < NEED) {   // deterministic guard
    (void)hipMemsetAsync(d_out, 0, (size_t)out_size * 4, stream);
    return;
  }

  unsigned short* xh  = (unsigned short*)(ws);             // 32MB
  unsigned short* xl  = (unsigned short*)(ws + 32 * MB);   // 32MB
  unsigned short* wh  = (unsigned short*)(ws + 64 * MB);   // 8MB
  unsigned short* wl  = (unsigned short*)(ws + 72 * MB);   // 8MB
  float* pre          = (float*)(ws + 80 * MB);            // 64MB (ends as gpre)
  __half* postk       = (__half*)(ws + 144 * MB);          // 32MB
  float* alphab       = (float*)(ws + 176 * MB);           // 512KB
  float* betab        = (float*)(ws + 176 * MB + 512 * 1024); // 512KB
  float* obuf         = (float*)ws;                        // overlaps xh/xl (dead)
  unsigned short* ybf = (unsigned short*)(ws + 144 * MB);  // overlaps postk (dead)
  __half* postv       = (__half*)d_out;                    // 32MB
  __half* postq       = (__half*)d_out + 16777216;         // 32MB

  dim3 gGemm(16, 64);   // (N/128, M/128)
  dim3 gT(64, 64);
  const int smemSplit = 4 * 4096 * 2;   // 32 KB
  const int smemPlain = 2 * 4096 * 2;   // 16 KB
  const float kscale = 0.08838834764831845f;  // 128^-0.5

  k_split<<<16384, 256, 0, stream>>>(x, xh, xl, 4194304);
  k_ab<<<8192, 256, 0, stream>>>(x, Wa, ba, Wb, bb, alphab, betab);

  k_transpose_split<<<gT, 256, 0, stream>>>(Wq, wh, wl, 2048, 2048);
  k_gemm<true><<<gGemm, 256, smemSplit, stream>>>(xh, xl, wh, wl, pre, 8192, 2048, 2048);
  k_conv<<<65536, 256, 0, stream>>>(pre, cqw, cqb, postq, 1.f);

  k_transpose_split<<<gT, 256, 0, stream>>>(Wk, wh, wl, 2048, 2048);
  k_gemm<true><<<gGemm, 256, smemSplit, stream>>>(xh, xl, wh, wl, pre, 8192, 2048, 2048);
  k_conv<<<65536, 256, 0, stream>>>(pre, ckw, ckb, postk, kscale);

  k_transpose_split<<<gT, 256, 0, stream>>>(Wv, wh, wl, 2048, 2048);
  k_gemm<true><<<gGemm, 256, smemSplit, stream>>>(xh, xl, wh, wl, pre, 8192, 2048, 2048);
  k_conv<<<65536, 256, 0, stream>>>(pre, cvw, cvb, postv, 1.f);

  k_transpose_split<<<gT, 256, 0, stream>>>(Wg, wh, nullptr, 2048, 2048);
  k_gemm<false><<<gGemm, 256, smemPlain, stream>>>(xh, nullptr, wh, nullptr, pre, 8192, 2048, 2048);

  k_recur<<<256, 512, 0, stream>>>(postq, postk, postv, alphab, betab, obuf);
  k_lngate<<<32768, 256, 0, stream>>>(obuf, pre, lng, lnb, ybf);

  k_transpose_split<<<gT, 256, 0, stream>>>(Wo, wh, nullptr, 2048, 2048);
  k_gemm<false><<<gGemm, 256, smemPlain, stream>>>(ybf, nullptr, wh, nullptr, (float*)d_out, 8192, 2048, 2048);
}

// Round 4
// 1886.343 us; speedup vs baseline: 1.4311x; 1.2082x over previous
//
#include <hip/hip_runtime.h>
#include <hip/hip_fp16.h>
#include <cstdint>
#include <cstddef>

// ---------------------------------------------------------------------------
// Gated delta-rule block for MI355X (gfx950).  R4:
//  - All big GEMMs now single-pass f16 MFMA (was 3-term split-bf16):
//    stage1: x @ [Wq|Wk] -> preI  [8192][4096] f16
//    stage2: x @ [Wv|Wg] -> preII [8192][4096] f16
//    final : y @ WoT     -> d_out fp32
//  - k_recur unchanged (LDS-BW bound, 627us; chunked WY deferred)
// Workspace 177MB used, 178MB guard:
//   [0,32)   xf16 -> postk f16 -> y f16     (sequential lifetimes)
//   [32,48)  wcat f16 (per-stage weights)
//   [32,96)  obuf fp32 (after GEMMs; overlays wcat+dead preI half)
//   [48,112) preI f16 (q|k)  — dead after convs
//   [96,112) woT f16 (after recur)
//   [112,176) preII f16 (v|g) — g half live until lngate
//   [176,177) alpha, beta fp32
//   d_out:   postq f16 [0,32MB) + postv f16 [32,64MB) -> final output fp32
// ---------------------------------------------------------------------------

typedef __attribute__((ext_vector_type(8))) _Float16 f16x8;  // 8 f16 = 4 VGPRs
typedef __attribute__((ext_vector_type(4))) float f32x4;

#define DEV __device__ __forceinline__

DEV float sigm(float z) { return 1.f / (1.f + expf(-z)); }

// DPP cross-lane add (VALU pipe only)
#define DPP_STEP(x, ctrl) \
  (x) = (x) + __int_as_float(__builtin_amdgcn_update_dpp( \
            0, __float_as_int(x), (ctrl), 0xF, 0xF, true))

// ----------------------------------------------------------------- x -> f16
__global__ __launch_bounds__(256)
void k_cvt(const float* __restrict__ x, _Float16* __restrict__ out, int n4) {
  int i = blockIdx.x * 256 + threadIdx.x;
  if (i >= n4) return;
  float4 v = ((const float4*)x)[i];
  _Float16 h[4] = {(_Float16)v.x, (_Float16)v.y, (_Float16)v.z, (_Float16)v.w};
  *(uint2*)(out + 4 * (size_t)i) = *(uint2*)h;
}

// ------------------------------------- weight transpose+concat -> f16 [N][K]
// dst row n: n < Nhalf -> col n of WA, else col n-Nhalf of WB. src stride 2048.
__global__ __launch_bounds__(256)
void k_wcat(const float* __restrict__ WA, const float* __restrict__ WB,
            _Float16* __restrict__ dst, int Kd, int Nhalf) {
  __shared__ float tile[32][33];
  int nb = blockIdx.x * 32, kb = blockIdx.y * 32;
  const float* W = (nb < Nhalf) ? WA : WB;
  int nc0 = (nb < Nhalf) ? nb : nb - Nhalf;
  int tx = threadIdx.x & 31, ty = threadIdx.x >> 5;   // 32 x 8
#pragma unroll
  for (int r = 0; r < 32; r += 8)
    tile[ty + r][tx] = W[(size_t)(kb + ty + r) * 2048 + nc0 + tx];
  __syncthreads();
#pragma unroll
  for (int r = 0; r < 32; r += 8) {
    int n = nb + ty + r, kk = kb + tx;
    dst[(size_t)n * Kd + kk] = (_Float16)tile[tx][ty + r];
  }
}

// ------------------------------------------------------------- alpha / beta
__global__ __launch_bounds__(256)
void k_ab(const float* __restrict__ x, const float* __restrict__ Wa,
          const float* __restrict__ ba, const float* __restrict__ Wb,
          const float* __restrict__ bb, float* __restrict__ alpha,
          float* __restrict__ beta) {
  __shared__ float xs[2048];
  int r = blockIdx.x;
  const float* xr = x + (size_t)r * 2048;
  for (int i = threadIdx.x; i < 2048; i += 256) xs[i] = xr[i];
  __syncthreads();
  int c = threadIdx.x >> 3, e = threadIdx.x & 7;
  int cc = c & 15;
  const float* W = (c < 16) ? Wa : Wb;
  const float* wp = W + cc;
  float s = 0.f;
  for (int k = e * 256; k < e * 256 + 256; k++) s += xs[k] * wp[(size_t)k * 16];
  s += __shfl_xor(s, 1); s += __shfl_xor(s, 2); s += __shfl_xor(s, 4);
  if (e == 0) {
    float bias = (c < 16) ? ba[cc] : bb[cc];
    float v = sigm(s + bias);
    if (c < 16) alpha[(size_t)r * 16 + cc] = v;
    else        beta [(size_t)r * 16 + cc] = v;
  }
}

// --------------------------------------------------------------------- GEMM
// C[M][N] = A[M][K] @ Bt[N][K]^T, f16 inputs, m97 structure:
// linear [128][32] LDS tiles via global_load_lds w=16, BK=32, 4 waves 2x2,
// each wave 64x64 = 4x4 16x16x32 f16 frags.  OUTF16: store f16, else fp32.
#define GLDS16(gsrc, ldst)                                                     \
  __builtin_amdgcn_global_load_lds(                                            \
      (const __attribute__((address_space(1))) unsigned int*)(gsrc),           \
      (__attribute__((address_space(3))) unsigned int*)(ldst), 16, 0, 0)

template <bool OUTF16>
__global__ __launch_bounds__(256)
void k_gemm16(const _Float16* __restrict__ A, const _Float16* __restrict__ B,
              void* __restrict__ Cout, int M, int N, int Kd) {
  extern __shared__ _Float16 smem[];
  _Float16* sA = smem;            // [128][32] = 8KB
  _Float16* sB = sA + 4096;

  int tid = threadIdx.x;
  int row0 = blockIdx.y * 128, col0 = blockIdx.x * 128;
  int w = tid >> 6, lane = tid & 63;

  // staging: wave w instr j covers LDS elems [(2w+j)*512 + lane*8)
  //   -> tile row (2w+j)*16 + (lane>>2), k-col (lane&3)*8
  int sr0 = w * 32 + (lane >> 2);
  int sc  = (lane & 3) * 8;
  size_t d0 = (size_t)w * 1024 + (size_t)lane * 8;
  size_t d1 = d0 + 512;
  const _Float16* gA0 = A + (size_t)(row0 + sr0) * Kd + sc;
  const _Float16* gA1 = gA0 + (size_t)16 * Kd;
  const _Float16* gB0 = B + (size_t)(col0 + sr0) * Kd + sc;
  const _Float16* gB1 = gB0 + (size_t)16 * Kd;

  int wrB = (w >> 1) * 64, wcB = (w & 1) * 64;
  int fr = lane & 15, kg = lane >> 4;
  size_t aoff = (size_t)(wrB + fr) * 32 + kg * 8;
  size_t boff = (size_t)(wcB + fr) * 32 + kg * 8;

  f32x4 acc[4][4];
#pragma unroll
  for (int m = 0; m < 4; m++)
#pragma unroll
    for (int n = 0; n < 4; n++)
#pragma unroll
      for (int r = 0; r < 4; r++) acc[m][n][r] = 0.f;

  for (int k0 = 0; k0 < Kd; k0 += 32) {
    GLDS16(gA0 + k0, sA + d0);
    GLDS16(gA1 + k0, sA + d1);
    GLDS16(gB0 + k0, sB + d0);
    GLDS16(gB1 + k0, sB + d1);
    __syncthreads();

    f16x8 af[4], bf[4];
#pragma unroll
    for (int i = 0; i < 4; i++) {
      af[i] = *(const f16x8*)(sA + aoff + (size_t)i * 512);
      bf[i] = *(const f16x8*)(sB + boff + (size_t)i * 512);
    }
#pragma unroll
    for (int m = 0; m < 4; m++)
#pragma unroll
      for (int n = 0; n < 4; n++)
        acc[m][n] = __builtin_amdgcn_mfma_f32_16x16x32_f16(af[m], bf[n], acc[m][n], 0, 0, 0);
    __syncthreads();
  }
  // C/D layout (m89-verified): col = lane&15, row = (lane>>4)*4 + reg
#pragma unroll
  for (int m = 0; m < 4; m++) {
    int rb = row0 + wrB + m * 16 + kg * 4;
#pragma unroll
    for (int n = 0; n < 4; n++) {
      int cb = col0 + wcB + n * 16 + fr;
#pragma unroll
      for (int r = 0; r < 4; r++) {
        if (OUTF16)
          ((_Float16*)Cout)[(size_t)(rb + r) * N + cb] = (_Float16)acc[m][n][r];
        else
          ((float*)Cout)[(size_t)(rb + r) * N + cb] = acc[m][n][r];
      }
    }
  }
}

// ---------------------------------------------------- causal conv K=4 + silu
// pre is f16 [8192][ldp], selected matrix at coloff; writes f16 post [8192][2048]
__global__ __launch_bounds__(256)
void k_conv(const _Float16* __restrict__ pre, int ldp, int coloff,
            const float* __restrict__ w, const float* __restrict__ bias,
            _Float16* __restrict__ post, float scale) {
  int idx = blockIdx.x * 256 + threadIdx.x;   // over B*T*C = 16,777,216
  int c = idx & 2047;
  int t = (idx >> 11) & 2047;
  int row = idx >> 11;
  const _Float16* p = pre + (size_t)row * ldp + coloff + c;
  float acc = bias[c];
  const float4 wv = *(const float4*)(w + 4 * (size_t)c);
  if (t >= 3) acc += wv.x * (float)p[-3 * ldp];
  if (t >= 2) acc += wv.y * (float)p[-2 * ldp];
  if (t >= 1) acc += wv.z * (float)p[-ldp];
  acc += wv.w * (float)p[0];
  post[idx] = (_Float16)(scale * (acc / (1.f + expf(-acc))));
}

// ---------------------------------------------------------------- recurrence
// grid = B*H*4 = 256 blocks x 512 threads (8 waves).
// thread: row r = tid>>4 (32 rows), k-group e = tid&15 (8 elems each).
// S in regs (8 f32).  16-lane reduce = pure DPP (ror8,ror4,qp2,qp1).
// LDS k/q cols swizzled: col(g) = 8g + 4(g>>2) -> 2-way banks.
__global__ __launch_bounds__(512)
void k_recur(const __half* __restrict__ q, const __half* __restrict__ k,
             const __half* __restrict__ v, const float* __restrict__ alpha,
             const float* __restrict__ beta, float* __restrict__ o) {
  constexpr int TB = 32;
  __shared__ float ks[TB][144], qs[TB][144];
  __shared__ float vs[TB][32], os[TB][32];
  __shared__ float as_[TB], bs_[TB];
  int blk = blockIdx.x;
  int quad = blk & 3, bh = blk >> 2;
  int b = bh >> 4, h = bh & 15;
  int tid = threadIdx.x;
  int r = tid >> 4, e = tid & 15;
  int cf = e * 8 + (e >> 2) * 4;
  const size_t base = ((size_t)b * 2048) * 2048 + (size_t)h * 128;
  const __half* qb = q + base;
  const __half* kb = k + base;
  const __half* vb = v + base + quad * 32;
  const float* ap = alpha + ((size_t)b * 2048) * 16 + h;
  const float* bp = beta  + ((size_t)b * 2048) * 16 + h;
  float* ob = o + base + quad * 32;

  float S[8];
#pragma unroll
  for (int i = 0; i < 8; i++) S[i] = 0.f;

  for (int t0 = 0; t0 < 2048; t0 += TB) {
    {   // stage k,q
      int tt = tid >> 4, g = tid & 15, col = g * 8 + (g >> 2) * 4;
      union { uint4 u; __half hh[8]; } pk, pq;
      pk.u = *(const uint4*)(kb + (size_t)(t0 + tt) * 2048 + g * 8);
      pq.u = *(const uint4*)(qb + (size_t)(t0 + tt) * 2048 + g * 8);
      float fk[8], fq[8];
#pragma unroll
      for (int j = 0; j < 8; j++) { fk[j] = __half2float(pk.hh[j]); fq[j] = __half2float(pq.hh[j]); }
      *(float4*)&ks[tt][col]     = *(float4*)(fk);
      *(float4*)&ks[tt][col + 4] = *(float4*)(fk + 4);
      *(float4*)&qs[tt][col]     = *(float4*)(fq);
      *(float4*)&qs[tt][col + 4] = *(float4*)(fq + 4);
    }
    if (tid < 256) {   // stage v
      int tt = tid >> 3, d4 = (tid & 7) * 4;
      union { unsigned long long u; __half hh[4]; } pv;
      pv.u = *(const unsigned long long*)(vb + (size_t)(t0 + tt) * 2048 + d4);
      float4 fv = {__half2float(pv.hh[0]), __half2float(pv.hh[1]),
                   __half2float(pv.hh[2]), __half2float(pv.hh[3])};
      *(float4*)&vs[tt][d4] = fv;
    }
    if (tid < TB) {
      as_[tid] = ap[(size_t)(t0 + tid) * 16];
      bs_[tid] = bp[(size_t)(t0 + tid) * 16];
    }
    __syncthreads();

    for (int tt = 0; tt < TB; tt++) {
      float kk[8], qq[8];
      *(float4*)(kk)     = *(const float4*)&ks[tt][cf];
      *(float4*)(kk + 4) = *(const float4*)&ks[tt][cf + 4];
      *(float4*)(qq)     = *(const float4*)&qs[tt][cf];
      *(float4*)(qq + 4) = *(const float4*)&qs[tt][cf + 4];
      float p = 0.f;
#pragma unroll
      for (int i = 0; i < 8; i++) p += S[i] * kk[i];
      DPP_STEP(p, 0x128);
      DPP_STEP(p, 0x124);
      DPP_STEP(p, 0x4E);
      DPP_STEP(p, 0xB1);
      float a = as_[tt];
      float cm = bs_[tt] * (p - vs[tt][r]);
      float og = 0.f;
#pragma unroll
      for (int i = 0; i < 8; i++) {
        S[i] = a * S[i] - cm * kk[i];
        og += S[i] * qq[i];
      }
      DPP_STEP(og, 0x128);
      DPP_STEP(og, 0x124);
      DPP_STEP(og, 0x4E);
      DPP_STEP(og, 0xB1);
      if (e == 0) os[tt][r] = og;
    }
    __syncthreads();
    for (int i = tid; i < TB * 32; i += 512) {
      int tt = i >> 5, d = i & 31;
      ob[(size_t)(t0 + tt) * 2048 + d] = os[tt][d];
    }
    __syncthreads();
  }
}

// ----------------------------------------------------- LayerNorm * gate -> y
// gpre = preII with g at cols [2048,4096): idx = (row>>4)*4096 + 2048 + (row&15)*128 + d
__global__ __launch_bounds__(256)
void k_lngate(const float* __restrict__ o, const _Float16* __restrict__ preII,
              const float* __restrict__ ln_g, const float* __restrict__ ln_b,
              _Float16* __restrict__ y) {
  int row = blockIdx.x * 4 + (threadIdx.x >> 6);   // 0 .. B*T*H-1
  int l = threadIdx.x & 63;
  const float* op = o + (size_t)row * 128;
  float2 xv = *(const float2*)(op + l * 2);
  float s = xv.x + xv.y;
#pragma unroll
  for (int off = 1; off < 64; off <<= 1) s += __shfl_xor(s, off);
  float mu = s * (1.f / 128.f);
  float d0 = xv.x - mu, d1 = xv.y - mu;
  float vv = d0 * d0 + d1 * d1;
#pragma unroll
  for (int off = 1; off < 64; off <<= 1) vv += __shfl_xor(vv, off);
  float rstd = 1.f / sqrtf(vv * (1.f / 128.f) + 1e-5f);
  int d = l * 2;
  size_t gidx = (size_t)(row >> 4) * 4096 + 2048 + (size_t)(row & 15) * 128 + d;
  float g0 = sigm((float)preII[gidx]);
  float g1 = sigm((float)preII[gidx + 1]);
  float y0 = (d0 * rstd * ln_g[d]     + ln_b[d])     * g0;
  float y1 = (d1 * rstd * ln_g[d + 1] + ln_b[d + 1]) * g1;
  size_t yb = (size_t)row * 128 + d;
  _Float16 hp[2] = {(_Float16)y0, (_Float16)y1};
  *(unsigned int*)(y + yb) = *(unsigned int*)hp;
}

// ---------------------------------------------------------------------------
extern "C" void kernel_launch(void* const* d_in, const int* in_sizes, int n_in,
                              void* d_out, int out_size, void* d_ws, size_t ws_size,
                              hipStream_t stream) {
  const float* x   = (const float*)d_in[0];
  const float* Wq  = (const float*)d_in[1];
  const float* Wk  = (const float*)d_in[2];
  const float* Wv  = (const float*)d_in[3];
  const float* Wa  = (const float*)d_in[4];
  const float* ba  = (const float*)d_in[5];
  const float* Wb  = (const float*)d_in[6];
  const float* bb  = (const float*)d_in[7];
  const float* Wg  = (const float*)d_in[8];
  const float* Wo  = (const float*)d_in[9];
  const float* cqw = (const float*)d_in[10];
  const float* cqb = (const float*)d_in[11];
  const float* ckw = (const float*)d_in[12];
  const float* ckb = (const float*)d_in[13];
  const float* cvw = (const float*)d_in[14];
  const float* cvb = (const float*)d_in[15];
  const float* lng = (const float*)d_in[16];
  const float* lnb = (const float*)d_in[17];

  char* ws = (char*)d_ws;
  const size_t MB = 1024 * 1024;
  const size_t NEED = 178 * MB;
  if (ws_size < NEED) {   // deterministic guard
    (void)hipMemsetAsync(d_out, 0, (size_t)out_size * 4, stream);
    return;
  }

  _Float16* xf16  = (_Float16*)(ws);                  // [0,32)
  _Float16* wcat  = (_Float16*)(ws + 32 * MB);        // [32,48)
  _Float16* preI  = (_Float16*)(ws + 48 * MB);        // [48,112)  q|k
  _Float16* preII = (_Float16*)(ws + 112 * MB);       // [112,176) v|g
  float* alphab   = (float*)(ws + 176 * MB);
  float* betab    = (float*)(ws + 176 * MB + 512 * 1024);
  _Float16* postk = (_Float16*)(ws);                  // reuse [0,32)
  float* obuf     = (float*)(ws + 32 * MB);           // [32,96)
  _Float16* ybuf  = (_Float16*)(ws);                  // reuse [0,32)
  _Float16* woT   = (_Float16*)(ws + 96 * MB);        // [96,112)
  _Float16* postq = (_Float16*)d_out;                 // d_out [0,32MB)
  _Float16* postv = (_Float16*)d_out + 16777216;      // d_out [32,64MB)

  dim3 gFused(32, 64);   // (N/128=32, M/128=64)
  dim3 gFinal(16, 64);
  const int smem16 = 2 * 4096 * 2;   // 16 KB
  const float kscale = 0.08838834764831845f;  // 128^-0.5

  k_cvt<<<16384, 256, 0, stream>>>(x, xf16, 4194304);
  k_ab<<<8192, 256, 0, stream>>>(x, Wa, ba, Wb, bb, alphab, betab);

  // stage 1: x @ [Wq|Wk] -> preI
  k_wcat<<<dim3(128, 64), 256, 0, stream>>>(Wq, Wk, wcat, 2048, 2048);
  k_gemm16<true><<<gFused, 256, smem16, stream>>>(xf16, wcat, preI, 8192, 4096, 2048);
  // stage 2: x @ [Wv|Wg] -> preII
  k_wcat<<<dim3(128, 64), 256, 0, stream>>>(Wv, Wg, wcat, 2048, 2048);
  k_gemm16<true><<<gFused, 256, smem16, stream>>>(xf16, wcat, preII, 8192, 4096, 2048);

  // convs (xf16 dead now; postk overwrites it)
  k_conv<<<65536, 256, 0, stream>>>(preI, 4096, 0,    cqw, cqb, postq, 1.f);
  k_conv<<<65536, 256, 0, stream>>>(preI, 4096, 2048, ckw, ckb, postk, kscale);
  k_conv<<<65536, 256, 0, stream>>>(preII, 4096, 0,   cvw, cvb, postv, 1.f);

  k_recur<<<256, 512, 0, stream>>>((const __half*)postq, (const __half*)postk,
                                   (const __half*)postv, alphab, betab, obuf);
  k_lngate<<<32768, 256, 0, stream>>>(obuf, preII, lng, lnb, ybuf);

  k_wcat<<<dim3(64, 64), 256, 0, stream>>>(Wo, Wo, woT, 2048, 2048);
  k_gemm16<false><<<gFinal, 256, smem16, stream>>>(ybuf, woT, d_out, 8192, 2048, 2048);
}